// Round 1
// baseline (52620.288 us; speedup 1.0000x reference)
//
#include <hip/hip_runtime.h>

namespace {
constexpr int kB = 16, kT = 512, kIN = 16, kD = 128, kH = 256, kL = 136, kO = 32;
constexpr int kSteps = kT - 1;      // 511
constexpr int NBLK = 256;           // one block per (d, l-half)
constexpr int NTHR = 512;
constexpr int LH   = 68;            // l per block (half of 136)
constexpr int PW   = 260;           // padded LDS row stride in floats (bank-conflict break)
constexpr int LDS_FLOATS = LH*PW + kB*PW + kB*kD + kB*LH + LH + 16*8 + kH;
constexpr size_t LDS_BYTES = (size_t)LDS_FLOATS * sizeof(float);
}

__device__ __forceinline__ float softplusf(float x) {
  // stable: max(x,0) + log1p(exp(-|x|))  (== jax.nn.softplus)
  return fmaxf(x, 0.0f) + log1pf(expf(-fabsf(x)));
}

// sense-reversing grid barrier, device scope
__device__ __forceinline__ void gbar(unsigned* cnt, unsigned* gen) {
  __syncthreads();
  if (threadIdx.x == 0) {
    __threadfence();  // release my block's prior global writes
    unsigned g = __hip_atomic_load(gen, __ATOMIC_RELAXED, __HIP_MEMORY_SCOPE_AGENT);
    unsigned arrived = __hip_atomic_fetch_add(cnt, 1u, __ATOMIC_ACQ_REL, __HIP_MEMORY_SCOPE_AGENT);
    if (arrived == (unsigned)(NBLK - 1)) {
      __hip_atomic_store(cnt, 0u, __ATOMIC_RELAXED, __HIP_MEMORY_SCOPE_AGENT);
      __hip_atomic_store(gen, g + 1u, __ATOMIC_RELEASE, __HIP_MEMORY_SCOPE_AGENT);
    } else {
      while (__hip_atomic_load(gen, __ATOMIC_ACQUIRE, __HIP_MEMORY_SCOPE_AGENT) == g) {
        __builtin_amdgcn_s_sleep(1);
      }
    }
  }
  __syncthreads();
}

__global__ void __launch_bounds__(256)
rde_init(const float* __restrict__ x0,
         const float* __restrict__ iw1, const float* __restrict__ ib1,
         const float* __restrict__ iw2, const float* __restrict__ ib2,
         const float* __restrict__ iw3, const float* __restrict__ ib3,
         float* __restrict__ hist) {
  __shared__ float xs[kIN];
  __shared__ __align__(16) float t1[kH];
  __shared__ __align__(16) float t2[kH];
  const int b = blockIdx.x, tid = threadIdx.x;
  if (tid < kIN) xs[tid] = x0[b*kIN + tid];
  __syncthreads();
  {
    float a = ib1[tid];
#pragma unroll
    for (int i = 0; i < kIN; ++i) a = fmaf(xs[i], iw1[tid*kIN + i], a);
    t1[tid] = softplusf(a);
  }
  __syncthreads();
  {
    const float4* wr = (const float4*)(iw2 + (size_t)tid*kH);
    float a = ib2[tid];
#pragma unroll 8
    for (int q = 0; q < kH/4; ++q) {
      float4 w = wr[q];
      a = fmaf(t1[4*q+0], w.x, a); a = fmaf(t1[4*q+1], w.y, a);
      a = fmaf(t1[4*q+2], w.z, a); a = fmaf(t1[4*q+3], w.w, a);
    }
    t2[tid] = softplusf(a);
  }
  __syncthreads();
  if (tid < kD) {
    const float4* wr = (const float4*)(iw3 + (size_t)tid*kH);
    float a = ib3[tid];
#pragma unroll 8
    for (int q = 0; q < kH/4; ++q) {
      float4 w = wr[q];
      a = fmaf(t2[4*q+0], w.x, a); a = fmaf(t2[4*q+1], w.y, a);
      a = fmaf(t2[4*q+2], w.z, a); a = fmaf(t2[4*q+3], w.w, a);
    }
    hist[(size_t)b*kD + tid] = a;   // hist[t=0][b][d]
  }
}

// persistent cooperative scan kernel
__global__ void __launch_bounds__(NTHR, 1)
rde_scan(const float* __restrict__ lsg,
         const float* __restrict__ fw1, const float* __restrict__ fb1,
         const float* __restrict__ fw2, const float* __restrict__ fb2,
         const float* __restrict__ fw3, const float* __restrict__ fb3,
         float* __restrict__ hist, float* z2g, float* partg, unsigned* bar) {
  extern __shared__ float lds[];
  float* w3s  = lds;                 // [LH][PW]  fw3 slice, padded
  float* z2s  = w3s + LH*PW;         // [kB][PW]
  float* hs   = z2s + kB*PW;         // [kB][kD]  full running h, replicated
  float* oms  = hs  + kB*kD;         // [kB][LH]  logsig slice
  float* fb3s = oms + kB*LH;         // [LH]
  float* red  = fb3s + LH;           // [16][8]
  float* z1s  = red + 16*8;          // [kH]      phase-1 scratch

  const int tid = threadIdx.x;
  const int k   = blockIdx.x;
  const int d_own = k >> 1;
  const int l0    = (k & 1) * LH;
  const int rowbase = d_own * kL + l0;

  // preload fw3 slice (68 rows x 256) into padded LDS — once for the whole scan
  for (int i = tid; i < LH*(kH/4); i += NTHR) {
    int r = i >> 6, q = i & 63;
    float4 v = *(const float4*)(fw3 + (size_t)(rowbase + r)*kH + 4*q);
    *(float4*)(w3s + r*PW + 4*q) = v;
  }
  for (int i = tid; i < LH; i += NTHR) fb3s[i] = fb3[rowbase + i];
  for (int i = tid; i < kB*kD; i += NTHR) hs[i] = hist[i];   // h0
  __syncthreads();

  unsigned* cnt = bar;
  unsigned* gen = bar + 1;

  for (int t = 0; t < kSteps; ++t) {
    // ---------- phase 1: blocks 0..15 compute z1 -> z2 for b = k ----------
    if (k < kB) {
      const int b = k;
      if (tid < kH) {
        const float4* hr = (const float4*)(hs + b*kD);
        const float4* wr = (const float4*)(fw1 + (size_t)tid*kD);
        float ax=0.f, ay=0.f, az=0.f, aw=0.f;
#pragma unroll 8
        for (int q = 0; q < kD/4; ++q) {
          float4 hv = hr[q], wv = wr[q];
          ax = fmaf(hv.x, wv.x, ax); ay = fmaf(hv.y, wv.y, ay);
          az = fmaf(hv.z, wv.z, az); aw = fmaf(hv.w, wv.w, aw);
        }
        z1s[tid] = softplusf((ax+ay)+(az+aw) + fb1[tid]);
      }
      if (tid < kD)  // record h_t
        hist[((size_t)t*kB + b)*kD + tid] = hs[b*kD + tid];
      __syncthreads();
      if (tid < kH) {
        const float4* zr = (const float4*)z1s;
        const float4* wr = (const float4*)(fw2 + (size_t)tid*kH);
        float ax=0.f, ay=0.f, az=0.f, aw=0.f;
#pragma unroll 16
        for (int q = 0; q < kH/4; ++q) {
          float4 zv = zr[q], wv = wr[q];
          ax = fmaf(zv.x, wv.x, ax); ay = fmaf(zv.y, wv.y, ay);
          az = fmaf(zv.z, wv.z, az); aw = fmaf(zv.w, wv.w, aw);
        }
        float v = softplusf((ax+ay)+(az+aw) + fb2[tid]);
        __hip_atomic_store(z2g + b*kH + tid, v, __ATOMIC_RELAXED, __HIP_MEMORY_SCOPE_AGENT);
      }
    }
    gbar(cnt, gen);

    // ---------- phase 3: all blocks, layer-3 dot + tanh + contraction ----------
    for (int i = tid; i < kB*kH; i += NTHR) {
      int bb = i >> 8, hh = i & (kH-1);
      z2s[bb*PW + hh] = __hip_atomic_load(z2g + i, __ATOMIC_RELAXED, __HIP_MEMORY_SCOPE_AGENT);
    }
    for (int i = tid; i < kB*LH; i += NTHR) {
      int bb = i / LH, ll = i - bb*LH;
      oms[i] = lsg[((size_t)bb*kSteps + t)*kL + l0 + ll];
    }
    __syncthreads();

    const int b3 = tid & 15;
    const int lb = tid >> 4;     // 0..31
    float psum;
    {
      const float4* zr = (const float4*)(z2s + b3*PW);
      const float4* w0 = (const float4*)(w3s + lb*PW);
      const float4* w1 = (const float4*)(w3s + (lb+32)*PW);
      float a0x=0.f,a0y=0.f,a0z=0.f,a0w=0.f;
      float a1x=0.f,a1y=0.f,a1z=0.f,a1w=0.f;
#pragma unroll 8
      for (int q = 0; q < kH/4; ++q) {
        float4 z = zr[q];
        float4 u = w0[q];
        a0x = fmaf(z.x,u.x,a0x); a0y = fmaf(z.y,u.y,a0y);
        a0z = fmaf(z.z,u.z,a0z); a0w = fmaf(z.w,u.w,a0w);
        float4 v = w1[q];
        a1x = fmaf(z.x,v.x,a1x); a1y = fmaf(z.y,v.y,a1y);
        a1z = fmaf(z.z,v.z,a1z); a1w = fmaf(z.w,v.w,a1w);
      }
      float s0 = (a0x+a0y)+(a0z+a0w) + fb3s[lb];
      float s1 = (a1x+a1y)+(a1z+a1w) + fb3s[lb+32];
      psum = tanhf(s0)*oms[b3*LH+lb] + tanhf(s1)*oms[b3*LH+lb+32];
      if (lb < LH - 64) {        // wave 0 only (lb<4): third l row
        const float4* w2 = (const float4*)(w3s + (lb+64)*PW);
        float a2x=0.f,a2y=0.f,a2z=0.f,a2w=0.f;
#pragma unroll 8
        for (int q = 0; q < kH/4; ++q) {
          float4 z = zr[q], u = w2[q];
          a2x = fmaf(z.x,u.x,a2x); a2y = fmaf(z.y,u.y,a2y);
          a2z = fmaf(z.z,u.z,a2z); a2w = fmaf(z.w,u.w,a2w);
        }
        float s2 = (a2x+a2y)+(a2z+a2w) + fb3s[lb+64];
        psum += tanhf(s2)*oms[b3*LH+lb+64];
      }
    }
    // reduce over l-threads sharing b: 4 lanes/wave, then 8 waves via LDS
    psum += __shfl_xor(psum, 16);
    psum += __shfl_xor(psum, 32);
    {
      int lane = tid & 63, wv = tid >> 6;
      if (lane < 16) red[lane*8 + wv] = psum;
    }
    __syncthreads();
    if (tid < 16) {
      float s = 0.f;
#pragma unroll
      for (int j = 0; j < 8; ++j) s += red[tid*8 + j];
      __hip_atomic_store(partg + (k*16 + tid), s, __ATOMIC_RELAXED, __HIP_MEMORY_SCOPE_AGENT);
    }
    gbar(cnt, gen);

    // ---------- phase 5: every block updates its replicated h ----------
    for (int i = tid; i < kB*kD; i += NTHR) {
      int bb = i >> 7, dd = i & (kD-1);
      float p0 = __hip_atomic_load(partg + (dd*2    )*16 + bb, __ATOMIC_RELAXED, __HIP_MEMORY_SCOPE_AGENT);
      float p1 = __hip_atomic_load(partg + (dd*2 + 1)*16 + bb, __ATOMIC_RELAXED, __HIP_MEMORY_SCOPE_AGENT);
      hs[i] += p0 + p1;
    }
    __syncthreads();
  }

  // final state h_{T-1} -> hist[511]
  if (k < kB && tid < kD)
    hist[((size_t)kSteps*kB + k)*kD + tid] = hs[k*kD + tid];
}

__global__ void __launch_bounds__(512)
rde_readout(const float* __restrict__ hist, const float* __restrict__ rw,
            const float* __restrict__ rb, float* __restrict__ out) {
  const int t = blockIdx.x, tid = threadIdx.x;
  const int b = tid >> 5, o = tid & 31;
  const float4* hr = (const float4*)(hist + ((size_t)t*kB + b)*kD);
  const float4* wr = (const float4*)(rw + (size_t)o*kD);
  float a = rb[o];
#pragma unroll 8
  for (int q = 0; q < kD/4; ++q) {
    float4 h4 = hr[q], w4 = wr[q];
    a = fmaf(h4.x,w4.x,a); a = fmaf(h4.y,w4.y,a);
    a = fmaf(h4.z,w4.z,a); a = fmaf(h4.w,w4.w,a);
  }
  out[((size_t)b*kT + t)*kO + o] = a;
}

extern "C" void kernel_launch(void* const* d_in, const int* in_sizes, int n_in,
                              void* d_out, int out_size, void* d_ws, size_t ws_size,
                              hipStream_t stream) {
  const float* x0  = (const float*)d_in[0];
  const float* lsg = (const float*)d_in[1];
  const float* iw1 = (const float*)d_in[2];
  const float* ib1 = (const float*)d_in[3];
  const float* iw2 = (const float*)d_in[4];
  const float* ib2 = (const float*)d_in[5];
  const float* iw3 = (const float*)d_in[6];
  const float* ib3 = (const float*)d_in[7];
  const float* fw1 = (const float*)d_in[8];
  const float* fb1 = (const float*)d_in[9];
  const float* fw2 = (const float*)d_in[10];
  const float* fb2 = (const float*)d_in[11];
  const float* fw3 = (const float*)d_in[12];
  const float* fb3 = (const float*)d_in[13];
  const float* rw  = (const float*)d_in[14];
  const float* rb  = (const float*)d_in[15];
  float* out = (float*)d_out;

  float*    hist  = (float*)d_ws;                     // kT*kB*kD
  float*    z2g   = hist + (size_t)kT*kB*kD;          // kB*kH
  float*    partg = z2g + kB*kH;                      // NBLK*16
  unsigned* bar   = (unsigned*)(partg + NBLK*16);     // 2

  hipMemsetAsync(bar, 0, 2*sizeof(unsigned), stream);
  hipFuncSetAttribute((const void*)rde_scan,
                      hipFuncAttributeMaxDynamicSharedMemorySize, (int)LDS_BYTES);

  rde_init<<<kB, 256, 0, stream>>>(x0, iw1, ib1, iw2, ib2, iw3, ib3, hist);

  void* args[] = { (void*)&lsg, (void*)&fw1, (void*)&fb1, (void*)&fw2, (void*)&fb2,
                   (void*)&fw3, (void*)&fb3, (void*)&hist, (void*)&z2g, (void*)&partg,
                   (void*)&bar };
  hipLaunchCooperativeKernel((const void*)rde_scan, dim3(NBLK), dim3(NTHR),
                             args, (unsigned)LDS_BYTES, stream);

  rde_readout<<<kT, 512, 0, stream>>>(hist, rw, rb, out);
}

// Round 2
// 18542.995 us; speedup vs baseline: 2.8377x; 2.8377x over previous
//
#include <hip/hip_runtime.h>

namespace {
constexpr int kB = 16, kT = 512, kIN = 16, kD = 128, kH = 256, kL = 136, kO = 32;
constexpr int kSteps = kT - 1;      // 511
constexpr int NBLK = 256;           // one block per (d, l-half)
constexpr int NTHR = 512;
constexpr int LH   = 68;            // l per block (half of 136)
constexpr int PW   = 260;           // padded LDS row stride in floats (bank-conflict break)
constexpr int FPAD = 32;            // 128B padding per barrier flag (own cache line)
constexpr int LDS_FLOATS = LH*PW + kB*PW + kB*kD + kB*LH + LH + 16*8 + kH;
constexpr size_t LDS_BYTES = (size_t)LDS_FLOATS * sizeof(float);
}

__device__ __forceinline__ float softplusf(float x) {
  // stable: max(x,0) + log1p(exp(-|x|))  (== jax.nn.softplus)
  return fmaxf(x, 0.0f) + log1pf(expf(-fabsf(x)));
}

// Flag-array grid barrier: no atomic RMW anywhere.
// Each block posts its epoch to a private 128B-padded flag (parallel stores);
// block 0 polls all flags with 256 threads (parallel loads), then publishes
// `go`; everyone else polls `go`. Latency ~2 coherence-point RTTs.
__device__ __forceinline__ void gbar(unsigned* flags, unsigned* go, unsigned ep,
                                     int k, int tid) {
  __syncthreads();
  if (k == 0) {
    if (tid > 0 && tid < NBLK) {
      while (__hip_atomic_load(&flags[(size_t)tid * FPAD], __ATOMIC_RELAXED,
                               __HIP_MEMORY_SCOPE_AGENT) < ep) {
        __builtin_amdgcn_s_sleep(1);
      }
    }
    __syncthreads();
    if (tid == 0) {
      __builtin_amdgcn_fence(__ATOMIC_ACQUIRE, "agent");   // pull others' data
      __hip_atomic_store(go, ep, __ATOMIC_RELEASE, __HIP_MEMORY_SCOPE_AGENT);
    }
    __syncthreads();
  } else {
    if (tid == 0) {
      __hip_atomic_store(&flags[(size_t)k * FPAD], ep, __ATOMIC_RELEASE,
                         __HIP_MEMORY_SCOPE_AGENT);
      while (__hip_atomic_load(go, __ATOMIC_RELAXED,
                               __HIP_MEMORY_SCOPE_AGENT) < ep) {
        __builtin_amdgcn_s_sleep(1);
      }
      __builtin_amdgcn_fence(__ATOMIC_ACQUIRE, "agent");
    }
    __syncthreads();
  }
}

__global__ void __launch_bounds__(256)
rde_init(const float* __restrict__ x0,
         const float* __restrict__ iw1, const float* __restrict__ ib1,
         const float* __restrict__ iw2, const float* __restrict__ ib2,
         const float* __restrict__ iw3, const float* __restrict__ ib3,
         float* __restrict__ hist) {
  __shared__ float xs[kIN];
  __shared__ __align__(16) float t1[kH];
  __shared__ __align__(16) float t2[kH];
  const int b = blockIdx.x, tid = threadIdx.x;
  if (tid < kIN) xs[tid] = x0[b*kIN + tid];
  __syncthreads();
  {
    float a = ib1[tid];
#pragma unroll
    for (int i = 0; i < kIN; ++i) a = fmaf(xs[i], iw1[tid*kIN + i], a);
    t1[tid] = softplusf(a);
  }
  __syncthreads();
  {
    const float4* wr = (const float4*)(iw2 + (size_t)tid*kH);
    float a = ib2[tid];
#pragma unroll 8
    for (int q = 0; q < kH/4; ++q) {
      float4 w = wr[q];
      a = fmaf(t1[4*q+0], w.x, a); a = fmaf(t1[4*q+1], w.y, a);
      a = fmaf(t1[4*q+2], w.z, a); a = fmaf(t1[4*q+3], w.w, a);
    }
    t2[tid] = softplusf(a);
  }
  __syncthreads();
  if (tid < kD) {
    const float4* wr = (const float4*)(iw3 + (size_t)tid*kH);
    float a = ib3[tid];
#pragma unroll 8
    for (int q = 0; q < kH/4; ++q) {
      float4 w = wr[q];
      a = fmaf(t2[4*q+0], w.x, a); a = fmaf(t2[4*q+1], w.y, a);
      a = fmaf(t2[4*q+2], w.z, a); a = fmaf(t2[4*q+3], w.w, a);
    }
    hist[(size_t)b*kD + tid] = a;   // hist[t=0][b][d]
  }
}

// persistent cooperative scan kernel
__global__ void __launch_bounds__(NTHR, 1)
rde_scan(const float* __restrict__ lsg,
         const float* __restrict__ fw1, const float* __restrict__ fb1,
         const float* __restrict__ fw2, const float* __restrict__ fb2,
         const float* __restrict__ fw3, const float* __restrict__ fb3,
         float* __restrict__ hist, float* z2g, float* partg,
         unsigned* flags, unsigned* go) {
  extern __shared__ float lds[];
  float* w3s  = lds;                 // [LH][PW]  fw3 slice, padded
  float* z2s  = w3s + LH*PW;         // [kB][PW]
  float* hs   = z2s + kB*PW;         // [kB][kD]  full running h, replicated
  float* oms  = hs  + kB*kD;         // [kB][LH]  logsig slice
  float* fb3s = oms + kB*LH;         // [LH]
  float* red  = fb3s + LH;           // [16][8]
  float* z1s  = red + 16*8;          // [kH]      phase-1 scratch

  const int tid = threadIdx.x;
  const int k   = blockIdx.x;
  const int d_own = k >> 1;
  const int l0    = (k & 1) * LH;
  const int rowbase = d_own * kL + l0;

  // preload fw3 slice (68 rows x 256) into padded LDS — once for the whole scan
  for (int i = tid; i < LH*(kH/4); i += NTHR) {
    int r = i >> 6, q = i & 63;
    float4 v = *(const float4*)(fw3 + (size_t)(rowbase + r)*kH + 4*q);
    *(float4*)(w3s + r*PW + 4*q) = v;
  }
  for (int i = tid; i < LH; i += NTHR) fb3s[i] = fb3[rowbase + i];
  for (int i = tid; i < kB*kD; i += NTHR) hs[i] = hist[i];   // h0
  __syncthreads();

  unsigned ep = 0;

  for (int t = 0; t < kSteps; ++t) {
    // ---------- phase 1: blocks 0..15 compute z1 -> z2 for b = k ----------
    if (k < kB) {
      const int b = k;
      if (tid < kH) {
        const float4* hr = (const float4*)(hs + b*kD);
        const float4* wr = (const float4*)(fw1 + (size_t)tid*kD);
        float ax=0.f, ay=0.f, az=0.f, aw=0.f;
#pragma unroll 8
        for (int q = 0; q < kD/4; ++q) {
          float4 hv = hr[q], wv = wr[q];
          ax = fmaf(hv.x, wv.x, ax); ay = fmaf(hv.y, wv.y, ay);
          az = fmaf(hv.z, wv.z, az); aw = fmaf(hv.w, wv.w, aw);
        }
        z1s[tid] = softplusf((ax+ay)+(az+aw) + fb1[tid]);
      }
      if (tid < kD)  // record h_t
        hist[((size_t)t*kB + b)*kD + tid] = hs[b*kD + tid];
      __syncthreads();
      if (tid < kH) {
        const float4* zr = (const float4*)z1s;
        const float4* wr = (const float4*)(fw2 + (size_t)tid*kH);
        float ax=0.f, ay=0.f, az=0.f, aw=0.f;
#pragma unroll 16
        for (int q = 0; q < kH/4; ++q) {
          float4 zv = zr[q], wv = wr[q];
          ax = fmaf(zv.x, wv.x, ax); ay = fmaf(zv.y, wv.y, ay);
          az = fmaf(zv.z, wv.z, az); aw = fmaf(zv.w, wv.w, aw);
        }
        float v = softplusf((ax+ay)+(az+aw) + fb2[tid]);
        __hip_atomic_store(z2g + b*kH + tid, v, __ATOMIC_RELAXED, __HIP_MEMORY_SCOPE_AGENT);
      }
    }
    ++ep; gbar(flags, go, ep, k, tid);

    // ---------- phase 3: all blocks, layer-3 dot + tanh + contraction ----------
    for (int i = tid; i < kB*kH; i += NTHR) {
      int bb = i >> 8, hh = i & (kH-1);
      z2s[bb*PW + hh] = __hip_atomic_load(z2g + i, __ATOMIC_RELAXED, __HIP_MEMORY_SCOPE_AGENT);
    }
    for (int i = tid; i < kB*LH; i += NTHR) {
      int bb = i / LH, ll = i - bb*LH;
      oms[i] = lsg[((size_t)bb*kSteps + t)*kL + l0 + ll];
    }
    __syncthreads();

    const int b3 = tid & 15;
    const int lb = tid >> 4;     // 0..31
    float psum;
    {
      const float4* zr = (const float4*)(z2s + b3*PW);
      const float4* w0 = (const float4*)(w3s + lb*PW);
      const float4* w1 = (const float4*)(w3s + (lb+32)*PW);
      float a0x=0.f,a0y=0.f,a0z=0.f,a0w=0.f;
      float a1x=0.f,a1y=0.f,a1z=0.f,a1w=0.f;
#pragma unroll 8
      for (int q = 0; q < kH/4; ++q) {
        float4 z = zr[q];
        float4 u = w0[q];
        a0x = fmaf(z.x,u.x,a0x); a0y = fmaf(z.y,u.y,a0y);
        a0z = fmaf(z.z,u.z,a0z); a0w = fmaf(z.w,u.w,a0w);
        float4 v = w1[q];
        a1x = fmaf(z.x,v.x,a1x); a1y = fmaf(z.y,v.y,a1y);
        a1z = fmaf(z.z,v.z,a1z); a1w = fmaf(z.w,v.w,a1w);
      }
      float s0 = (a0x+a0y)+(a0z+a0w) + fb3s[lb];
      float s1 = (a1x+a1y)+(a1z+a1w) + fb3s[lb+32];
      psum = tanhf(s0)*oms[b3*LH+lb] + tanhf(s1)*oms[b3*LH+lb+32];
      if (lb < LH - 64) {        // wave 0 only (lb<4): third l row
        const float4* w2 = (const float4*)(w3s + (lb+64)*PW);
        float a2x=0.f,a2y=0.f,a2z=0.f,a2w=0.f;
#pragma unroll 8
        for (int q = 0; q < kH/4; ++q) {
          float4 z = zr[q], u = w2[q];
          a2x = fmaf(z.x,u.x,a2x); a2y = fmaf(z.y,u.y,a2y);
          a2z = fmaf(z.z,u.z,a2z); a2w = fmaf(z.w,u.w,a2w);
        }
        float s2 = (a2x+a2y)+(a2z+a2w) + fb3s[lb+64];
        psum += tanhf(s2)*oms[b3*LH+lb+64];
      }
    }
    // reduce over l-threads sharing b: 4 lanes/wave, then 8 waves via LDS
    psum += __shfl_xor(psum, 16);
    psum += __shfl_xor(psum, 32);
    {
      int lane = tid & 63, wv = tid >> 6;
      if (lane < 16) red[lane*8 + wv] = psum;
    }
    __syncthreads();
    if (tid < 16) {
      float s = 0.f;
#pragma unroll
      for (int j = 0; j < 8; ++j) s += red[tid*8 + j];
      __hip_atomic_store(partg + (k*16 + tid), s, __ATOMIC_RELAXED, __HIP_MEMORY_SCOPE_AGENT);
    }
    ++ep; gbar(flags, go, ep, k, tid);

    // ---------- phase 5: every block updates its replicated h ----------
    for (int i = tid; i < kB*kD; i += NTHR) {
      int bb = i >> 7, dd = i & (kD-1);
      float p0 = __hip_atomic_load(partg + (dd*2    )*16 + bb, __ATOMIC_RELAXED, __HIP_MEMORY_SCOPE_AGENT);
      float p1 = __hip_atomic_load(partg + (dd*2 + 1)*16 + bb, __ATOMIC_RELAXED, __HIP_MEMORY_SCOPE_AGENT);
      hs[i] += p0 + p1;
    }
    __syncthreads();
  }

  // final state h_{T-1} -> hist[511]
  if (k < kB && tid < kD)
    hist[((size_t)kSteps*kB + k)*kD + tid] = hs[k*kD + tid];
}

__global__ void __launch_bounds__(512)
rde_readout(const float* __restrict__ hist, const float* __restrict__ rw,
            const float* __restrict__ rb, float* __restrict__ out) {
  const int t = blockIdx.x, tid = threadIdx.x;
  const int b = tid >> 5, o = tid & 31;
  const float4* hr = (const float4*)(hist + ((size_t)t*kB + b)*kD);
  const float4* wr = (const float4*)(rw + (size_t)o*kD);
  float a = rb[o];
#pragma unroll 8
  for (int q = 0; q < kD/4; ++q) {
    float4 h4 = hr[q], w4 = wr[q];
    a = fmaf(h4.x,w4.x,a); a = fmaf(h4.y,w4.y,a);
    a = fmaf(h4.z,w4.z,a); a = fmaf(h4.w,w4.w,a);
  }
  out[((size_t)b*kT + t)*kO + o] = a;
}

extern "C" void kernel_launch(void* const* d_in, const int* in_sizes, int n_in,
                              void* d_out, int out_size, void* d_ws, size_t ws_size,
                              hipStream_t stream) {
  const float* x0  = (const float*)d_in[0];
  const float* lsg = (const float*)d_in[1];
  const float* iw1 = (const float*)d_in[2];
  const float* ib1 = (const float*)d_in[3];
  const float* iw2 = (const float*)d_in[4];
  const float* ib2 = (const float*)d_in[5];
  const float* iw3 = (const float*)d_in[6];
  const float* ib3 = (const float*)d_in[7];
  const float* fw1 = (const float*)d_in[8];
  const float* fb1 = (const float*)d_in[9];
  const float* fw2 = (const float*)d_in[10];
  const float* fb2 = (const float*)d_in[11];
  const float* fw3 = (const float*)d_in[12];
  const float* fb3 = (const float*)d_in[13];
  const float* rw  = (const float*)d_in[14];
  const float* rb  = (const float*)d_in[15];
  float* out = (float*)d_out;

  float*    hist  = (float*)d_ws;                     // kT*kB*kD
  float*    z2g   = hist + (size_t)kT*kB*kD;          // kB*kH
  float*    partg = z2g + kB*kH;                      // NBLK*16
  unsigned* flags = (unsigned*)(partg + NBLK*16);     // NBLK*FPAD
  unsigned* go    = flags + (size_t)NBLK*FPAD;        // 1 (own line)

  hipMemsetAsync(flags, 0, ((size_t)NBLK*FPAD + 32) * sizeof(unsigned), stream);
  hipFuncSetAttribute((const void*)rde_scan,
                      hipFuncAttributeMaxDynamicSharedMemorySize, (int)LDS_BYTES);

  rde_init<<<kB, 256, 0, stream>>>(x0, iw1, ib1, iw2, ib2, iw3, ib3, hist);

  void* args[] = { (void*)&lsg, (void*)&fw1, (void*)&fb1, (void*)&fw2, (void*)&fb2,
                   (void*)&fw3, (void*)&fb3, (void*)&hist, (void*)&z2g, (void*)&partg,
                   (void*)&flags, (void*)&go };
  hipLaunchCooperativeKernel((const void*)rde_scan, dim3(NBLK), dim3(NTHR),
                             args, (unsigned)LDS_BYTES, stream);

  rde_readout<<<kT, 512, 0, stream>>>(hist, rw, rb, out);
}

// Round 3
// 4502.889 us; speedup vs baseline: 11.6859x; 4.1180x over previous
//
#include <hip/hip_runtime.h>

namespace {
constexpr int kB = 16, kT = 512, kIN = 16, kD = 128, kH = 256, kL = 136, kO = 32;
constexpr int kSteps = kT - 1;      // 511
constexpr int NBLK = 256;           // block k: d = k>>1, l-half = k&1
constexpr int NTHR = 512;
constexpr int LH   = 68;            // l per block
constexpr int NTILE = 5;            // 5 MFMA n-tiles (80 cols, 68 real)
constexpr int FS   = 32;            // flag stride in dwords (128B)
// LDS layout (bytes)
constexpr int OFF_FW1 = 0;                       // [128][64] f32 k-major  32768
constexpr int OFF_FW2 = 32768;                   // [256][64] f32 k-major  65536
constexpr int OFF_AHI = 98304;                   // [16][264] bf16          8448
constexpr int OFF_ALO = 106752;                  // [16][264] bf16          8448
constexpr int OFF_DT  = 115200;                  // [16][84]  f32           5376
constexpr int OFF_OMS = 120576;                  // [16][68]  f32           4352
constexpr int OFF_Z1S = 124928;                  // [256]     f32           1024
constexpr int OFF_HB  = 125952;                  // [128]     f32            512
constexpr int OFF_RED = 126464;                  // [16][8]   f32            512
constexpr size_t LDS_BYTES = 126976;
}

typedef __attribute__((ext_vector_type(8))) short short8;
typedef __attribute__((ext_vector_type(4))) float f32x4;

__device__ __forceinline__ float softplusf(float x) {
  return fmaxf(x, 0.0f) + log1pf(expf(-fabsf(x)));
}
__device__ __forceinline__ unsigned short f2bf(float x) {
  unsigned u = __float_as_uint(x);
  return (unsigned short)((u + 0x7FFFu + ((u >> 16) & 1u)) >> 16);
}
__device__ __forceinline__ float bf2f(unsigned short h) {
  return __uint_as_float(((unsigned)h) << 16);
}
#define ALOADF(p)  __hip_atomic_load((p),  __ATOMIC_RELAXED, __HIP_MEMORY_SCOPE_AGENT)
#define ASTOREF(p,v) __hip_atomic_store((p), (v), __ATOMIC_RELAXED, __HIP_MEMORY_SCOPE_AGENT)

__global__ void __launch_bounds__(256)
rde_init(const float* __restrict__ x0,
         const float* __restrict__ iw1, const float* __restrict__ ib1,
         const float* __restrict__ iw2, const float* __restrict__ ib2,
         const float* __restrict__ iw3, const float* __restrict__ ib3,
         float* __restrict__ hist) {
  __shared__ float xs[kIN];
  __shared__ __align__(16) float t1[kH];
  __shared__ __align__(16) float t2[kH];
  const int b = blockIdx.x, tid = threadIdx.x;
  if (tid < kIN) xs[tid] = x0[b*kIN + tid];
  __syncthreads();
  {
    float a = ib1[tid];
#pragma unroll
    for (int i = 0; i < kIN; ++i) a = fmaf(xs[i], iw1[tid*kIN + i], a);
    t1[tid] = softplusf(a);
  }
  __syncthreads();
  {
    const float4* wr = (const float4*)(iw2 + (size_t)tid*kH);
    float a = ib2[tid];
#pragma unroll 8
    for (int q = 0; q < kH/4; ++q) {
      float4 w = wr[q];
      a = fmaf(t1[4*q+0], w.x, a); a = fmaf(t1[4*q+1], w.y, a);
      a = fmaf(t1[4*q+2], w.z, a); a = fmaf(t1[4*q+3], w.w, a);
    }
    t2[tid] = softplusf(a);
  }
  __syncthreads();
  if (tid < kD) {
    const float4* wr = (const float4*)(iw3 + (size_t)tid*kH);
    float a = ib3[tid];
#pragma unroll 8
    for (int q = 0; q < kH/4; ++q) {
      float4 w = wr[q];
      a = fmaf(t2[4*q+0], w.x, a); a = fmaf(t2[4*q+1], w.y, a);
      a = fmaf(t2[4*q+2], w.z, a); a = fmaf(t2[4*q+3], w.w, a);
    }
    hist[(size_t)b*kD + tid] = a;
  }
}

__global__ void __launch_bounds__(NTHR, 2)
rde_scan(const float* __restrict__ lsg,
         const float* __restrict__ fw1, const float* __restrict__ fb1,
         const float* __restrict__ fw2, const float* __restrict__ fb2,
         const float* __restrict__ fw3, const float* __restrict__ fb3,
         float* __restrict__ hist, float* z1g, float* z2g, float* partg,
         unsigned* z1fl, unsigned* z2fl, unsigned* pfl) {
  extern __shared__ char smem[];
  float* fw1s = (float*)(smem + OFF_FW1);          // [128][64] k-major
  float* fw2s = (float*)(smem + OFF_FW2);          // [256][64] k-major
  unsigned short* Ahi = (unsigned short*)(smem + OFF_AHI);  // [16][264]
  unsigned short* Alo = (unsigned short*)(smem + OFF_ALO);
  float* Dt  = (float*)(smem + OFF_DT);            // [16][84]
  float* oms = (float*)(smem + OFF_OMS);           // [16][68]
  float* z1s = (float*)(smem + OFF_Z1S);           // [256]
  float* hb  = (float*)(smem + OFF_HB);            // [128]
  float* red = (float*)(smem + OFF_RED);           // [16][8]

  const int tid  = threadIdx.x;
  const int k    = blockIdx.x;
  const int wave = tid >> 6, lane = tid & 63;
  const int d_own = k >> 1, l0 = (k & 1) * LH;
  const bool isMLP = (k < 64);
  const int bmlp = k >> 2, qm = k & 3, j0 = qm * 64;

  // ---------------- prologue ----------------
  // fw3 fragments -> VGPRs (waves 0-4, one 16-col tile each), hi/lo bf16 split
  short8 bhi[8], blo[8];
  float biasv = 0.f;
  {
#pragma unroll
    for (int s = 0; s < 8; ++s) { bhi[s] = (short8)0; blo[s] = (short8)0; }
    if (wave < NTILE) {
      const int nl = wave*16 + (lane & 15);
      const int g  = lane >> 4;
      if (nl < LH) {
        const size_t row = (size_t)d_own*kL + l0 + nl;
        const float* wrow = fw3 + row*kH;
        biasv = fb3[row];
#pragma unroll
        for (int s = 0; s < 8; ++s) {
          const int k0 = s*32 + g*8;
          float4 v0 = *(const float4*)(wrow + k0);
          float4 v1 = *(const float4*)(wrow + k0 + 4);
          float vv[8] = {v0.x,v0.y,v0.z,v0.w,v1.x,v1.y,v1.z,v1.w};
#pragma unroll
          for (int e = 0; e < 8; ++e) {
            unsigned short hh = f2bf(vv[e]);
            bhi[s][e] = (short)hh;
            blo[s][e] = (short)f2bf(vv[e] - bf2f(hh));
          }
        }
      }
    }
  }
  float myfb1 = 0.f, myfb2 = 0.f;
  if (isMLP) {
    if (tid < 256) { int j = tid >> 2; myfb1 = fb1[j0 + j]; myfb2 = fb2[j0 + j]; }
    // fw1 slice, k-major transpose: fw1s[k][j] = fw1[(j0+j)*128 + k]
    for (int i = tid; i < 64*32; i += NTHR) {
      int j = i >> 5, qq = i & 31;
      float4 v = *(const float4*)(fw1 + (size_t)(j0 + j)*kD + qq*4);
      fw1s[(qq*4+0)*64 + j] = v.x; fw1s[(qq*4+1)*64 + j] = v.y;
      fw1s[(qq*4+2)*64 + j] = v.z; fw1s[(qq*4+3)*64 + j] = v.w;
    }
    for (int i = tid; i < 64*64; i += NTHR) {
      int j = i >> 6, qq = i & 63;
      float4 v = *(const float4*)(fw2 + (size_t)(j0 + j)*kH + qq*4);
      fw2s[(qq*4+0)*64 + j] = v.x; fw2s[(qq*4+1)*64 + j] = v.y;
      fw2s[(qq*4+2)*64 + j] = v.z; fw2s[(qq*4+3)*64 + j] = v.w;
    }
    for (int i = tid; i < kD; i += NTHR) hb[i] = hist[(size_t)bmlp*kD + i];
  }
  __syncthreads();

  // ---------------- scan ----------------
  for (int t = 0; t < kSteps; ++t) {
    const unsigned epw = (unsigned)(t + 1);

    // prefetch lsg slice -> oms (threads 256-511; independent of z2)
    if (tid >= 256) {
      int c = tid - 256;                       // chunk 0..255 (+16 extra)
#pragma unroll 2
      for (int rep = 0; rep < 2; ++rep) {
        int cc = c + rep*256;
        if (cc < 272) {
          int bb = cc / 17, ii = cc % 17;
          float4 v = *(const float4*)(lsg + ((size_t)bb*kSteps + t)*kL + l0 + ii*4);
          *(float4*)(oms + bb*LH + ii*4) = v;
        }
      }
    }

    if (isMLP) {
      // ---- z1 quarter: j in [j0, j0+64), K=128 ----
      if (tid < 256) {
        int j = tid >> 2, ks = tid & 3;
        float a = 0.f;
#pragma unroll 8
        for (int kk = ks; kk < kD; kk += 4) a = fmaf(hb[kk], fw1s[kk*64 + j], a);
        a += __shfl_xor(a, 1); a += __shfl_xor(a, 2);
        if (ks == 0) ASTOREF(z1g + bmlp*kH + j0 + j, softplusf(a + myfb1));
      }
      __syncthreads();                          // drains vmcnt per wave
      if (tid == 0) __hip_atomic_store(z1fl + (bmlp*4 + qm)*FS, epw,
                                       __ATOMIC_RELAXED, __HIP_MEMORY_SCOPE_AGENT);
      // ---- wait 4 quarters of z1[b] ----
      if (tid < 4) {
        while (__hip_atomic_load(z1fl + (bmlp*4 + tid)*FS, __ATOMIC_RELAXED,
                                 __HIP_MEMORY_SCOPE_AGENT) < epw)
          __builtin_amdgcn_s_sleep(1);
      }
      __syncthreads();
      asm volatile("" ::: "memory");
      if (tid < 128) {
        unsigned long long v = __hip_atomic_load((const unsigned long long*)(z1g + bmlp*kH) + tid,
                                                 __ATOMIC_RELAXED, __HIP_MEMORY_SCOPE_AGENT);
        union { unsigned long long u; float2 f; } cv; cv.u = v;
        z1s[2*tid] = cv.f.x; z1s[2*tid + 1] = cv.f.y;
      }
      __syncthreads();
      // ---- z2 quarter: K=256 ----
      if (tid < 256) {
        int j = tid >> 2, ks = tid & 3;
        float a = 0.f;
#pragma unroll 8
        for (int kk = ks; kk < kH; kk += 4) a = fmaf(z1s[kk], fw2s[kk*64 + j], a);
        a += __shfl_xor(a, 1); a += __shfl_xor(a, 2);
        if (ks == 0) ASTOREF(z2g + bmlp*kH + j0 + j, softplusf(a + myfb2));
      }
      __syncthreads();
      if (tid == 0) __hip_atomic_store(z2fl + (bmlp*4 + qm)*FS, epw,
                                       __ATOMIC_RELAXED, __HIP_MEMORY_SCOPE_AGENT);
    }

    // ---- all blocks: wait full z2, read + hi/lo convert into A planes ----
    if (tid < 64) {
      while (__hip_atomic_load(z2fl + tid*FS, __ATOMIC_RELAXED,
                               __HIP_MEMORY_SCOPE_AGENT) < epw)
        __builtin_amdgcn_s_sleep(2);
    }
    __syncthreads();
    asm volatile("" ::: "memory");
#pragma unroll
    for (int i = 0; i < 4; ++i) {
      int p = tid*4 + i;                        // float-pair index 0..2047
      unsigned long long v = __hip_atomic_load((const unsigned long long*)z2g + p,
                                               __ATOMIC_RELAXED, __HIP_MEMORY_SCOPE_AGENT);
      union { unsigned long long u; float2 f; } cv; cv.u = v;
      int m = p >> 7, kk = (p & 127) * 2;
      unsigned short h0 = f2bf(cv.f.x), h1 = f2bf(cv.f.y);
      unsigned short e0 = f2bf(cv.f.x - bf2f(h0)), e1 = f2bf(cv.f.y - bf2f(h1));
      *(unsigned*)(Ahi + m*264 + kk) = (unsigned)h0 | ((unsigned)h1 << 16);
      *(unsigned*)(Alo + m*264 + kk) = (unsigned)e0 | ((unsigned)e1 << 16);
    }
    __syncthreads();

    // ---- MFMA: waves 0-4, tile = wave (16 cols), K=256, hi/lo 3-product ----
    if (wave < NTILE) {
      f32x4 acc = {biasv, biasv, biasv, biasv};
      const unsigned short* arh = Ahi + (lane & 15)*264;
      const unsigned short* arl = Alo + (lane & 15)*264;
      const int g = lane >> 4;
#pragma unroll
      for (int s = 0; s < 8; ++s) {
        short8 ah = *(const short8*)(arh + s*32 + g*8);
        short8 al = *(const short8*)(arl + s*32 + g*8);
        acc = __builtin_amdgcn_mfma_f32_16x16x32_bf16(ah, bhi[s], acc, 0, 0, 0);
        acc = __builtin_amdgcn_mfma_f32_16x16x32_bf16(ah, blo[s], acc, 0, 0, 0);
        acc = __builtin_amdgcn_mfma_f32_16x16x32_bf16(al, bhi[s], acc, 0, 0, 0);
      }
#pragma unroll
      for (int r = 0; r < 4; ++r)
        Dt[(g*4 + r)*84 + wave*16 + (lane & 15)] = acc[r];
    }
    __syncthreads();

    // ---- contraction: tanh * logsig, reduce over l ----
    {
      const int b3 = tid & 15, lb = tid >> 4;   // lb 0..31
      float p = tanhf(Dt[b3*84 + lb     ]) * oms[b3*LH + lb     ]
              + tanhf(Dt[b3*84 + lb + 32]) * oms[b3*LH + lb + 32];
      if (lb < 4)
        p += tanhf(Dt[b3*84 + lb + 64]) * oms[b3*LH + lb + 64];
      p += __shfl_xor(p, 16); p += __shfl_xor(p, 32);
      if (lane < 16) red[lane*8 + wave] = p;
    }
    __syncthreads();
    if (tid < 16) {
      float s = 0.f;
#pragma unroll
      for (int j = 0; j < 8; ++j) s += red[tid*8 + j];
      ASTOREF(partg + tid*256 + k, s);          // partg[b][k]
    }
    __syncthreads();
    if (tid == 0) __hip_atomic_store(pfl + k*FS, epw,
                                     __ATOMIC_RELAXED, __HIP_MEMORY_SCOPE_AGENT);

    // ---- MLP blocks: gather partials, update h ----
    if (isMLP) {
      if (tid < 256) {
        while (__hip_atomic_load(pfl + tid*FS, __ATOMIC_RELAXED,
                                 __HIP_MEMORY_SCOPE_AGENT) < epw)
          __builtin_amdgcn_s_sleep(2);
      }
      __syncthreads();
      asm volatile("" ::: "memory");
      if (tid < 128) {
        unsigned long long v = __hip_atomic_load((const unsigned long long*)(partg + bmlp*256) + tid,
                                                 __ATOMIC_RELAXED, __HIP_MEMORY_SCOPE_AGENT);
        union { unsigned long long u; float2 f; } cv; cv.u = v;
        hb[tid] += cv.f.x + cv.f.y;
      }
      __syncthreads();
      if (qm == 0 && tid < 128)
        hist[((size_t)(t+1)*kB + bmlp)*kD + tid] = hb[tid];
    }
  }
}

__global__ void __launch_bounds__(512)
rde_readout(const float* __restrict__ hist, const float* __restrict__ rw,
            const float* __restrict__ rb, float* __restrict__ out) {
  const int t = blockIdx.x, tid = threadIdx.x;
  const int b = tid >> 5, o = tid & 31;
  const float4* hr = (const float4*)(hist + ((size_t)t*kB + b)*kD);
  const float4* wr = (const float4*)(rw + (size_t)o*kD);
  float a = rb[o];
#pragma unroll 8
  for (int q = 0; q < kD/4; ++q) {
    float4 h4 = hr[q], w4 = wr[q];
    a = fmaf(h4.x,w4.x,a); a = fmaf(h4.y,w4.y,a);
    a = fmaf(h4.z,w4.z,a); a = fmaf(h4.w,w4.w,a);
  }
  out[((size_t)b*kT + t)*kO + o] = a;
}

extern "C" void kernel_launch(void* const* d_in, const int* in_sizes, int n_in,
                              void* d_out, int out_size, void* d_ws, size_t ws_size,
                              hipStream_t stream) {
  const float* x0  = (const float*)d_in[0];
  const float* lsg = (const float*)d_in[1];
  const float* iw1 = (const float*)d_in[2];
  const float* ib1 = (const float*)d_in[3];
  const float* iw2 = (const float*)d_in[4];
  const float* ib2 = (const float*)d_in[5];
  const float* iw3 = (const float*)d_in[6];
  const float* ib3 = (const float*)d_in[7];
  const float* fw1 = (const float*)d_in[8];
  const float* fb1 = (const float*)d_in[9];
  const float* fw2 = (const float*)d_in[10];
  const float* fb2 = (const float*)d_in[11];
  const float* fw3 = (const float*)d_in[12];
  const float* fb3 = (const float*)d_in[13];
  const float* rw  = (const float*)d_in[14];
  const float* rb  = (const float*)d_in[15];
  float* out = (float*)d_out;

  float*    hist  = (float*)d_ws;                       // 512*16*128
  float*    z1g   = hist + (size_t)kT*kB*kD;            // 4096
  float*    z2g   = z1g + kB*kH;                        // 4096
  float*    partg = z2g + kB*kH;                        // 4096  [b][256]
  unsigned* z1fl  = (unsigned*)(partg + kB*NBLK);       // 64*FS
  unsigned* z2fl  = z1fl + 64*FS;                       // 64*FS
  unsigned* pfl   = z2fl + 64*FS;                       // 256*FS

  hipMemsetAsync(z1fl, 0, (size_t)(64 + 64 + 256)*FS*sizeof(unsigned), stream);
  hipFuncSetAttribute((const void*)rde_scan,
                      hipFuncAttributeMaxDynamicSharedMemorySize, (int)LDS_BYTES);

  rde_init<<<kB, 256, 0, stream>>>(x0, iw1, ib1, iw2, ib2, iw3, ib3, hist);

  void* args[] = { (void*)&lsg, (void*)&fw1, (void*)&fb1, (void*)&fw2, (void*)&fb2,
                   (void*)&fw3, (void*)&fb3, (void*)&hist, (void*)&z1g, (void*)&z2g,
                   (void*)&partg, (void*)&z1fl, (void*)&z2fl, (void*)&pfl };
  hipLaunchCooperativeKernel((const void*)rde_scan, dim3(NBLK), dim3(NTHR),
                             args, (unsigned)LDS_BYTES, stream);

  rde_readout<<<kT, 512, 0, stream>>>(hist, rw, rb, out);
}